// Round 1
// baseline (264.538 us; speedup 1.0000x reference)
//
#include <hip/hip_runtime.h>
#include <hip/hip_bf16.h>

#define SIZE 6144
#define DDIM 2048
#define BHALF 2048
#define BIJ 4096

typedef __attribute__((ext_vector_type(8))) short bf16x8;
typedef __attribute__((ext_vector_type(4))) float f32x4;
typedef __attribute__((ext_vector_type(4))) unsigned int u32x4;

__device__ __forceinline__ float block_reduce_sum(float v, float* red) {
    // 256 threads = 4 waves
    #pragma unroll
    for (int off = 32; off; off >>= 1) v += __shfl_xor(v, off, 64);
    int lane = threadIdx.x & 63, wid = threadIdx.x >> 6;
    if (lane == 0) red[wid] = v;
    __syncthreads();
    float t = red[0] + red[1] + red[2] + red[3];
    __syncthreads();
    return t;
}

// One block (256 thr) per row: L2-normalize in fp32, write bf16 z, and
// dii[r] = ||z_bf16[r]||^2 (fp32) so the diagonal exp term cancels
// consistently with the MFMA-computed sim[i,i].
__global__ __launch_bounds__(256) void normalize_kernel(
    const float* __restrict__ ei, const float* __restrict__ ej,
    const float* __restrict__ ek,
    unsigned short* __restrict__ zb, float* __restrict__ dii)
{
    __shared__ float red[4];
    int r = blockIdx.x;
    const float* src = (r < BHALF)   ? (ei + (size_t)r * DDIM)
                     : (r < 2*BHALF) ? (ej + (size_t)(r - BHALF) * DDIM)
                                     : (ek + (size_t)(r - 2*BHALF) * DDIM);
    int t = threadIdx.x;
    float4 v0 = ((const float4*)src)[t*2];
    float4 v1 = ((const float4*)src)[t*2 + 1];
    float ss = v0.x*v0.x + v0.y*v0.y + v0.z*v0.z + v0.w*v0.w
             + v1.x*v1.x + v1.y*v1.y + v1.z*v1.z + v1.w*v1.w;
    float tot = block_reduce_sum(ss, red);
    float scale = 1.0f / fmaxf(sqrtf(tot), 1e-12f);

    float xs[8] = {v0.x, v0.y, v0.z, v0.w, v1.x, v1.y, v1.z, v1.w};
    unsigned short u[8];
    float d = 0.f;
    #pragma unroll
    for (int j = 0; j < 8; ++j) {
        __hip_bfloat16 h = __float2bfloat16(xs[j] * scale);
        u[j] = *(unsigned short*)&h;
        float f = __bfloat162float(h);
        d += f * f;
    }
    *(u32x4*)&zb[(size_t)r * DDIM + t*8] = *(u32x4*)u;
    float dtot = block_reduce_sum(d, red);
    if (t == 0) dii[r] = dtot;
}

// Fused: sim-tile (bf16 MFMA) -> exp(10*sim) -> per-row partial sums ->
// atomicAdd into S1 (cols < 4096) or S2 (cols >= 4096).
// 128x128 tile, BK=64, 4 waves (2x2), 16x16x32 MFMA, global_load_lds w16.
__global__ __launch_bounds__(256) void simexp_kernel(
    const unsigned short* __restrict__ zb, float* __restrict__ S)
{
    __shared__ short As[128 * 64];
    __shared__ short Bs[128 * 64];
    const int tid  = threadIdx.x;
    const int lane = tid & 63;
    const int w    = tid >> 6;       // wave 0..3
    const int wr   = w >> 1, wc = w & 1;
    const int rt = blockIdx.y, ct = blockIdx.x;
    const int rowA0 = rt * 128, colB0 = ct * 128;

    const int rowc = lane >> 3;        // 0..7 (row within 8-row chunk)
    const int kc   = (lane & 7) * 8;   // bf16 col within BK=64

    f32x4 acc[4][4] = {};

    const int lr = lane & 15;
    const int kh = (lane >> 4) * 8;

    for (int kt = 0; kt < DDIM; kt += 64) {
        __syncthreads();
        #pragma unroll
        for (int it = 0; it < 4; ++it) {
            int rchunk = it * 32 + w * 8;   // wave-uniform LDS chunk base
            const unsigned short* ga =
                zb + (size_t)(rowA0 + rchunk + rowc) * DDIM + kt + kc;
            __builtin_amdgcn_global_load_lds(
                (const __attribute__((address_space(1))) void*)ga,
                (__attribute__((address_space(3))) void*)&As[rchunk * 64],
                16, 0, 0);
            const unsigned short* gb =
                zb + (size_t)(colB0 + rchunk + rowc) * DDIM + kt + kc;
            __builtin_amdgcn_global_load_lds(
                (const __attribute__((address_space(1))) void*)gb,
                (__attribute__((address_space(3))) void*)&Bs[rchunk * 64],
                16, 0, 0);
        }
        __syncthreads();
        #pragma unroll
        for (int kk = 0; kk < 64; kk += 32) {
            bf16x8 af[4], bfr[4];
            #pragma unroll
            for (int mi = 0; mi < 4; ++mi)
                af[mi] = *(const bf16x8*)&As[(wr*64 + mi*16 + lr)*64 + kk + kh];
            #pragma unroll
            for (int ni = 0; ni < 4; ++ni)
                bfr[ni] = *(const bf16x8*)&Bs[(wc*64 + ni*16 + lr)*64 + kk + kh];
            #pragma unroll
            for (int mi = 0; mi < 4; ++mi)
                #pragma unroll
                for (int ni = 0; ni < 4; ++ni)
                    acc[mi][ni] = __builtin_amdgcn_mfma_f32_16x16x32_bf16(
                        af[mi], bfr[ni], acc[mi][ni], 0, 0, 0);
        }
    }

    // epilogue: exp + row-sum. C/D: row = (lane>>4)*4 + q (+mi*16), col = lane&15 (+ni*16)
    float rs[4][4];
    #pragma unroll
    for (int mi = 0; mi < 4; ++mi)
        #pragma unroll
        for (int q = 0; q < 4; ++q) {
            float s = 0.f;
            #pragma unroll
            for (int ni = 0; ni < 4; ++ni)
                s += __expf(10.0f * acc[mi][ni][q]);
            rs[mi][q] = s;
        }
    // reduce across the 16 col-lanes (lane bits 0..3)
    #pragma unroll
    for (int off = 1; off < 16; off <<= 1)
        #pragma unroll
        for (int mi = 0; mi < 4; ++mi)
            #pragma unroll
            for (int q = 0; q < 4; ++q)
                rs[mi][q] += __shfl_xor(rs[mi][q], off, 64);

    if ((lane & 15) == 0) {
        float* St = S + ((ct < BIJ / 128) ? 0 : SIZE);
        int rq = (lane >> 4) * 4;
        #pragma unroll
        for (int mi = 0; mi < 4; ++mi)
            #pragma unroll
            for (int q = 0; q < 4; ++q)
                atomicAdd(&St[rowA0 + wr*64 + mi*16 + rq + q], rs[mi][q]);
    }
}

__global__ void zero_kernel(float* __restrict__ p, int n) {
    int i = blockIdx.x * 256 + threadIdx.x;
    if (i < n) p[i] = 0.f;
}

// Single block: per-row loss terms, total, write scalar.
__global__ __launch_bounds__(256) void loss_kernel(
    const float* __restrict__ S, const float* __restrict__ dii,
    float* __restrict__ out)
{
    __shared__ float red[4];
    float local = 0.f;
    const float c1 = logf((float)(BIJ - 1));
    const float c2 = logf((float)(BHALF - 1));
    for (int r = threadIdx.x; r < SIZE; r += 256) {
        float s1 = S[r], s2 = S[SIZE + r];
        float eii = __expf(10.0f * dii[r]);
        float denom = s1 + s2 - eii;
        float num, c;
        if (r < BIJ) { num = s1 - eii; c = c1; }
        else         { num = s2 - eii; c = c2; }
        local += logf(denom) - logf(num) + c;
    }
    float tot = block_reduce_sum(local, red);
    if (threadIdx.x == 0) out[0] = tot / (float)SIZE;
}

extern "C" void kernel_launch(void* const* d_in, const int* in_sizes, int n_in,
                              void* d_out, int out_size, void* d_ws, size_t ws_size,
                              hipStream_t stream) {
    const float* ei = (const float*)d_in[0];
    const float* ej = (const float*)d_in[1];
    const float* ek = (const float*)d_in[2];
    float* out = (float*)d_out;

    char* ws = (char*)d_ws;
    unsigned short* zb = (unsigned short*)ws;                    // 6144*2048*2 = 25165824 B
    float* dii = (float*)(ws + 25165824);                        // 24576 B
    float* S   = (float*)(ws + 25165824 + 24576);                // 2*6144*4 = 49152 B

    zero_kernel<<<dim3(48), dim3(256), 0, stream>>>(S, 2 * SIZE);
    normalize_kernel<<<dim3(SIZE), dim3(256), 0, stream>>>(ei, ej, ek, zb, dii);
    simexp_kernel<<<dim3(48, 48), dim3(256), 0, stream>>>(zb, S);
    loss_kernel<<<dim3(1), dim3(256), 0, stream>>>(S, dii, out);
}

// Round 2
// 175.907 us; speedup vs baseline: 1.5039x; 1.5039x over previous
//
#include <hip/hip_runtime.h>
#include <hip/hip_bf16.h>

#define SIZE 6144
#define DDIM 2048
#define BHALF 2048
#define BIJ 4096
#define NT 48   // 6144 / 128 tiles per dim

typedef __attribute__((ext_vector_type(8))) short bf16x8;
typedef __attribute__((ext_vector_type(4))) float f32x4;
typedef __attribute__((ext_vector_type(4))) unsigned int u32x4;

__device__ __forceinline__ float block_reduce_sum(float v, float* red) {
    // 256 threads = 4 waves
    #pragma unroll
    for (int off = 32; off; off >>= 1) v += __shfl_xor(v, off, 64);
    int lane = threadIdx.x & 63, wid = threadIdx.x >> 6;
    if (lane == 0) red[wid] = v;
    __syncthreads();
    float t = red[0] + red[1] + red[2] + red[3];
    __syncthreads();
    return t;
}

// One block (256 thr) per row: L2-normalize in fp32, write bf16 z, and
// dii[r] = ||z_bf16[r]||^2 (fp32) so the diagonal exp term cancels
// consistently with the MFMA-computed sim[i,i].
__global__ __launch_bounds__(256) void normalize_kernel(
    const float* __restrict__ ei, const float* __restrict__ ej,
    const float* __restrict__ ek,
    unsigned short* __restrict__ zb, float* __restrict__ dii)
{
    __shared__ float red[4];
    int r = blockIdx.x;
    const float* src = (r < BHALF)   ? (ei + (size_t)r * DDIM)
                     : (r < 2*BHALF) ? (ej + (size_t)(r - BHALF) * DDIM)
                                     : (ek + (size_t)(r - 2*BHALF) * DDIM);
    int t = threadIdx.x;
    float4 v0 = ((const float4*)src)[t*2];
    float4 v1 = ((const float4*)src)[t*2 + 1];
    float ss = v0.x*v0.x + v0.y*v0.y + v0.z*v0.z + v0.w*v0.w
             + v1.x*v1.x + v1.y*v1.y + v1.z*v1.z + v1.w*v1.w;
    float tot = block_reduce_sum(ss, red);
    float scale = 1.0f / fmaxf(sqrtf(tot), 1e-12f);

    float xs[8] = {v0.x, v0.y, v0.z, v0.w, v1.x, v1.y, v1.z, v1.w};
    unsigned short u[8];
    float d = 0.f;
    #pragma unroll
    for (int j = 0; j < 8; ++j) {
        __hip_bfloat16 h = __float2bfloat16(xs[j] * scale);
        u[j] = *(unsigned short*)&h;
        float f = __bfloat162float(h);
        d += f * f;
    }
    *(u32x4*)&zb[(size_t)r * DDIM + t*8] = *(u32x4*)u;
    float dtot = block_reduce_sum(d, red);
    if (t == 0) dii[r] = dtot;
}

// Fused symmetric sim: upper-triangular tiles only (rt <= ct).
// Each tile: bf16 MFMA -> exp(10*sim) in-register ->
//   row-sums -> atomicAdd S[group(ct)][rows of rt-block]
//   col-sums (off-diag only) -> atomicAdd S[group(rt)][rows of ct-block]
// 128x128 tile, BK=64, 4 waves (2x2), 16x16x32 MFMA, global_load_lds w16.
__global__ __launch_bounds__(256) void simexp_kernel(
    const unsigned short* __restrict__ zb, float* __restrict__ S)
{
    __shared__ short As[128 * 64];
    __shared__ short Bs[128 * 64];

    // triangular decode: bid -> (rt, ct) with ct >= rt
    int rem = blockIdx.x;
    int rt = 0, width = NT;
    while (rem >= width) { rem -= width; ++rt; --width; }
    const int ct = rt + rem;

    const int tid  = threadIdx.x;
    const int lane = tid & 63;
    const int w    = tid >> 6;       // wave 0..3
    const int wr   = w >> 1, wc = w & 1;
    const int rowA0 = rt * 128, colB0 = ct * 128;

    const int rowc = lane >> 3;        // 0..7 (row within 8-row chunk)
    const int kc   = (lane & 7) * 8;   // bf16 col within BK=64

    f32x4 acc[4][4] = {};

    const int lr = lane & 15;
    const int kh = (lane >> 4) * 8;

    for (int kt = 0; kt < DDIM; kt += 64) {
        __syncthreads();
        #pragma unroll
        for (int it = 0; it < 4; ++it) {
            int rchunk = it * 32 + w * 8;   // wave-uniform LDS chunk base
            const unsigned short* ga =
                zb + (size_t)(rowA0 + rchunk + rowc) * DDIM + kt + kc;
            __builtin_amdgcn_global_load_lds(
                (const __attribute__((address_space(1))) void*)ga,
                (__attribute__((address_space(3))) void*)&As[rchunk * 64],
                16, 0, 0);
            const unsigned short* gb =
                zb + (size_t)(colB0 + rchunk + rowc) * DDIM + kt + kc;
            __builtin_amdgcn_global_load_lds(
                (const __attribute__((address_space(1))) void*)gb,
                (__attribute__((address_space(3))) void*)&Bs[rchunk * 64],
                16, 0, 0);
        }
        __syncthreads();
        #pragma unroll
        for (int kk = 0; kk < 64; kk += 32) {
            bf16x8 af[4], bfr[4];
            #pragma unroll
            for (int mi = 0; mi < 4; ++mi)
                af[mi] = *(const bf16x8*)&As[(wr*64 + mi*16 + lr)*64 + kk + kh];
            #pragma unroll
            for (int ni = 0; ni < 4; ++ni)
                bfr[ni] = *(const bf16x8*)&Bs[(wc*64 + ni*16 + lr)*64 + kk + kh];
            #pragma unroll
            for (int mi = 0; mi < 4; ++mi)
                #pragma unroll
                for (int ni = 0; ni < 4; ++ni)
                    acc[mi][ni] = __builtin_amdgcn_mfma_f32_16x16x32_bf16(
                        af[mi], bfr[ni], acc[mi][ni], 0, 0, 0);
        }
    }

    // exp in-register (reused for both row- and col-sums)
    #pragma unroll
    for (int mi = 0; mi < 4; ++mi)
        #pragma unroll
        for (int ni = 0; ni < 4; ++ni)
            #pragma unroll
            for (int q = 0; q < 4; ++q)
                acc[mi][ni][q] = __expf(10.0f * acc[mi][ni][q]);

    // ---- row-sums: C/D row = (lane>>4)*4 + q (+mi*16), col = lane&15 (+ni*16)
    {
        float rs[4][4];
        #pragma unroll
        for (int mi = 0; mi < 4; ++mi)
            #pragma unroll
            for (int q = 0; q < 4; ++q) {
                float s = 0.f;
                #pragma unroll
                for (int ni = 0; ni < 4; ++ni) s += acc[mi][ni][q];
                rs[mi][q] = s;
            }
        #pragma unroll
        for (int off = 1; off < 16; off <<= 1)
            #pragma unroll
            for (int mi = 0; mi < 4; ++mi)
                #pragma unroll
                for (int q = 0; q < 4; ++q)
                    rs[mi][q] += __shfl_xor(rs[mi][q], off, 64);

        if ((lane & 15) == 0) {
            float* St = S + ((ct < BIJ / 128) ? 0 : SIZE);
            int rq = (lane >> 4) * 4;
            #pragma unroll
            for (int mi = 0; mi < 4; ++mi)
                #pragma unroll
                for (int q = 0; q < 4; ++q)
                    atomicAdd(&St[rowA0 + wr*64 + mi*16 + rq + q], rs[mi][q]);
        }
    }

    // ---- col-sums (transpose contribution), off-diagonal tiles only
    if (rt != ct) {
        float cs[4];
        #pragma unroll
        for (int ni = 0; ni < 4; ++ni) {
            float s = 0.f;
            #pragma unroll
            for (int mi = 0; mi < 4; ++mi)
                #pragma unroll
                for (int q = 0; q < 4; ++q) s += acc[mi][ni][q];
            cs[ni] = s;
        }
        // reduce across the 4 row-groups (lane bits 4,5)
        #pragma unroll
        for (int off = 16; off < 64; off <<= 1)
            #pragma unroll
            for (int ni = 0; ni < 4; ++ni)
                cs[ni] += __shfl_xor(cs[ni], off, 64);

        if (lane < 16) {
            float* St = S + ((rt < BIJ / 128) ? 0 : SIZE);
            #pragma unroll
            for (int ni = 0; ni < 4; ++ni)
                atomicAdd(&St[colB0 + wc*64 + ni*16 + lane], cs[ni]);
        }
    }
}

__global__ void zero_kernel(float* __restrict__ p, int n) {
    int i = blockIdx.x * 256 + threadIdx.x;
    if (i < n) p[i] = 0.f;
}

// Single block: per-row loss terms, total, write scalar.
__global__ __launch_bounds__(256) void loss_kernel(
    const float* __restrict__ S, const float* __restrict__ dii,
    float* __restrict__ out)
{
    __shared__ float red[4];
    float local = 0.f;
    const float c1 = logf((float)(BIJ - 1));
    const float c2 = logf((float)(BHALF - 1));
    for (int r = threadIdx.x; r < SIZE; r += 256) {
        float s1 = S[r], s2 = S[SIZE + r];
        float eii = __expf(10.0f * dii[r]);
        float denom = s1 + s2 - eii;
        float num, c;
        if (r < BIJ) { num = s1 - eii; c = c1; }
        else         { num = s2 - eii; c = c2; }
        local += logf(denom) - logf(num) + c;
    }
    float tot = block_reduce_sum(local, red);
    if (threadIdx.x == 0) out[0] = tot / (float)SIZE;
}

extern "C" void kernel_launch(void* const* d_in, const int* in_sizes, int n_in,
                              void* d_out, int out_size, void* d_ws, size_t ws_size,
                              hipStream_t stream) {
    const float* ei = (const float*)d_in[0];
    const float* ej = (const float*)d_in[1];
    const float* ek = (const float*)d_in[2];
    float* out = (float*)d_out;

    char* ws = (char*)d_ws;
    unsigned short* zb = (unsigned short*)ws;                    // 6144*2048*2 = 25165824 B
    float* dii = (float*)(ws + 25165824);                        // 24576 B
    float* S   = (float*)(ws + 25165824 + 24576);                // 2*6144*4 = 49152 B

    zero_kernel<<<dim3(48), dim3(256), 0, stream>>>(S, 2 * SIZE);
    normalize_kernel<<<dim3(SIZE), dim3(256), 0, stream>>>(ei, ej, ek, zb, dii);
    simexp_kernel<<<dim3(NT * (NT + 1) / 2), dim3(256), 0, stream>>>(zb, S);
    loss_kernel<<<dim3(1), dim3(256), 0, stream>>>(S, dii, out);
}